// Round 1
// baseline (346.421 us; speedup 1.0000x reference)
//
#include <hip/hip_runtime.h>

#define NB 16
#define LL 32
#define NORD 24
#define NSTEPS 64
#define NV 512            // number of voltage states (also first current index)
#define MID 1024
#define NSTATE 1025
#define MMLEN (6 * LL * NB + 1)   // 3073

// trapezoidal pulse, f32 arithmetic replicating the jnp reference
__device__ __forceinline__ float pulsef(float ts) {
    const float rise = 5.0e-10f;
    const float w    = 9.999999999999999e-10f;   // PULSE_T2-PULSE_T1 in f64 -> f32
    const float fall = 5.0e-10f;
    const float e1   = 1.4999999999999998e-9f;   // width+rise
    const float e2   = 1.9999999999999997e-9f;   // width+rise+fall
    if (ts < rise) return ts / rise;
    if (ts < e1)   return 1.0f;
    if (ts < e2)   return 1.0f - ((ts - w) - rise) / fall;
    return 0.0f;
}

__global__ __launch_bounds__(1024) void sspuf_main(
    const int*   __restrict__ swp,
    const float* __restrict__ mismatch,
    const float* __restrict__ gm_c,
    const float* __restrict__ gm_l,
    const float* __restrict__ c_val,
    const float* __restrict__ l_val,
    const float* __restrict__ tp,
    float*       __restrict__ out)
{
    const int star = blockIdx.x;     // 0 or 1
    const int r    = threadIdx.x;    // row 0..1023 (mid=1024 handled by thread 0)
    const float dt = tp[0] / 64.0f;

    const float* mm = mismatch + star * MMLEN;

    // ---- per-row sparse coefficients of (A*dt): row r has <=2 nonzeros ----
    float P, Q;
    int idx0, idx1;
    if (r < NV) {
        // voltage row: dv[b,k]/dt = (gmc0*i[b,k] - gmc1*i[b,k+1]) / C[b,k]
        int b = r >> 5, k = r & 31;
        const float* mb = mm + b * 192;
        float gmc0 = mb[2 * k]     * gm_c[2 * k];
        float gmc1 = mb[2 * k + 1] * gm_c[2 * k + 1];
        float C    = 1e-9f * (mb[128 + k] * c_val[k]);
        P    = dt * (gmc0 / C);
        idx0 = NV + r;                       // i[b,k]
        Q    = (k < 31) ? (-dt * (gmc1 / C)) : 0.0f;
        idx1 = NV + r + 1;                   // i[b,k+1] (coef 0 at k=31; r=511 reads MID harmlessly)
    } else {
        // current row: di[b,k]/dt = (gml0*v[b,k-1] - gml1*v[b,k]) / L[b,k], v[b,-1]=sw*v_mid
        int rr = r - NV;
        int b = rr >> 5, k = rr & 31;
        const float* mb = mm + b * 192;
        float gml0 = mb[64 + 2 * k]     * gm_l[2 * k];
        float gml1 = mb[64 + 2 * k + 1] * gm_l[2 * k + 1];
        float Lm   = 1e-9f * (mb[160 + k] * l_val[k]);
        P    = -dt * (gml1 / Lm);
        idx0 = rr;                           // v[b,k]
        if (k == 0) {
            Q    = dt * (((float)swp[b]) * gml0 / Lm);
            idx1 = MID;                      // v_mid
        } else {
            Q    = dt * (gml0 / Lm);
            idx1 = rr - 1;                   // v[b,k-1]
        }
    }

    // ---- mid-row data (16 nonzeros): dv_mid/dt = (u - sum_b sw[b]*i[b,0]) / c_mid ----
    const float c_mid = 1e-9f * (mm[6 * LL * NB] * c_val[LL]);
    float cM[NB];
#pragma unroll
    for (int b = 0; b < NB; ++b) cM[b] = -dt * (((float)swp[b]) / c_mid);

    const bool ismid = (r == 0);
    const bool iscmp = (r >= NV) && ((r & 31) == 0);   // threads owning i[b,0]
    const int  cb    = (r - NV) >> 5;

    // ---- LDS: double-buffered state vector + compact copy of the 16 i[b,0] ----
    __shared__ float bufA[NSTATE + 3];
    __shared__ float bufB[NSTATE + 3];
    __shared__ __align__(16) float cmpA[NB];
    __shared__ __align__(16) float cmpB[NB];

    float* cur  = bufA; float* nxt  = bufB;
    float* ccur = cmpA; float* cnxt = cmpB;

    // ================= phib = Phi @ Bv via the series =================
    // w0 = Bv (only mid nonzero, = 1/c_mid); phib = sum_j w_j * dt/(j+1), w_j = (A dt w_{j-1})/j
    float phib_r   = 0.0f;
    float phib_mid = dt * (1.0f / c_mid);
    cur[r] = 0.0f;
    if (iscmp) ccur[cb] = 0.0f;
    if (ismid) cur[MID] = 1.0f / c_mid;
    __syncthreads();
#pragma unroll
    for (int j = 1; j <= NORD; ++j) {
        const float invj = 1.0f / (float)j;
        const float sc   = dt / (float)(j + 1);
        float tn = (P * cur[idx0] + Q * cur[idx1]) * invj;
        float midn = 0.0f;
        if (ismid) {
            const float4* c4 = (const float4*)ccur;
            float4 a0 = c4[0], a1 = c4[1], a2 = c4[2], a3 = c4[3];
            midn = cM[0]*a0.x + cM[1]*a0.y + cM[2]*a0.z + cM[3]*a0.w
                 + cM[4]*a1.x + cM[5]*a1.y + cM[6]*a1.z + cM[7]*a1.w
                 + cM[8]*a2.x + cM[9]*a2.y + cM[10]*a2.z + cM[11]*a2.w
                 + cM[12]*a3.x + cM[13]*a3.y + cM[14]*a3.z + cM[15]*a3.w;
            midn *= invj;
        }
        phib_r += tn * sc;
        nxt[r] = tn;
        if (iscmp) cnxt[cb] = tn;
        if (ismid) { nxt[MID] = midn; phib_mid += midn * sc; }
        __syncthreads();
        float* t0 = cur; cur = nxt; nxt = t0;
        t0 = ccur; ccur = cnxt; cnxt = t0;
    }

    // ================= 64 ZOH steps: x <- E x + phib*u =================
    float x_r = 0.0f;
    float x_mid = 0.0f;
    for (int step = 0; step < NSTEPS; ++step) {
        const float ts = ((float)step + 0.5f) * dt;
        const float u  = pulsef(ts);

        // stage x (term j=0) into cur
        cur[r] = x_r;
        if (iscmp) ccur[cb] = x_r;
        if (ismid) cur[MID] = x_mid;
        float acc = x_r;
        float acc_mid = x_mid;
        __syncthreads();

#pragma unroll
        for (int j = 1; j <= NORD; ++j) {
            const float invj = 1.0f / (float)j;
            float tn = (P * cur[idx0] + Q * cur[idx1]) * invj;
            float midn = 0.0f;
            if (ismid) {
                const float4* c4 = (const float4*)ccur;
                float4 a0 = c4[0], a1 = c4[1], a2 = c4[2], a3 = c4[3];
                midn = cM[0]*a0.x + cM[1]*a0.y + cM[2]*a0.z + cM[3]*a0.w
                     + cM[4]*a1.x + cM[5]*a1.y + cM[6]*a1.z + cM[7]*a1.w
                     + cM[8]*a2.x + cM[9]*a2.y + cM[10]*a2.z + cM[11]*a2.w
                     + cM[12]*a3.x + cM[13]*a3.y + cM[14]*a3.z + cM[15]*a3.w;
                midn *= invj;
            }
            acc += tn;
            nxt[r] = tn;
            if (iscmp) cnxt[cb] = tn;
            if (ismid) { nxt[MID] = midn; acc_mid += midn; }
            __syncthreads();
            float* t0 = cur; cur = nxt; nxt = t0;
            t0 = ccur; ccur = cnxt; cnxt = t0;
        }

        x_r = acc + phib_r * u;
        if (ismid) x_mid = acc_mid + phib_mid * u;
    }

    // output = x_mid(star 0) - x_mid(star 1); d_out was zeroed via memset
    if (ismid) atomicAdd(out, (star == 0) ? x_mid : -x_mid);
}

extern "C" void kernel_launch(void* const* d_in, const int* in_sizes, int n_in,
                              void* d_out, int out_size, void* d_ws, size_t ws_size,
                              hipStream_t stream) {
    const int*   swp      = (const int*)d_in[0];
    const float* mismatch = (const float*)d_in[1];
    const float* gm_c     = (const float*)d_in[2];
    const float* gm_l     = (const float*)d_in[3];
    const float* c_val    = (const float*)d_in[4];
    const float* l_val    = (const float*)d_in[5];
    const float* tp       = (const float*)d_in[6];
    float* out = (float*)d_out;

    hipMemsetAsync(out, 0, sizeof(float), stream);
    sspuf_main<<<dim3(2), dim3(1024), 0, stream>>>(
        swp, mismatch, gm_c, gm_l, c_val, l_val, tp, out);
}